// Round 1
// baseline (274.710 us; speedup 1.0000x reference)
//
#include <hip/hip_runtime.h>

#define BB 16
#define CC 512
#define SS 4096
#define GELEMS 262144   // 64 ch * 4096 spatial per group

typedef __attribute__((ext_vector_type(8))) __bf16 bf16x8;
typedef __attribute__((ext_vector_type(4))) float f32x4;
typedef __attribute__((ext_vector_type(4))) unsigned short us4;

__device__ __forceinline__ unsigned short f2bf(float f) {
  unsigned int u = __float_as_uint(f);
  u += 0x7fffu + ((u >> 16) & 1u);   // RNE
  return (unsigned short)(u >> 16);
}
__device__ __forceinline__ int qrow(int cv) { return ((cv >> 7) * 384) + 256 + (cv & 127); }

__device__ __forceinline__ void gl_lds16(const void* g, void* l) {
  __builtin_amdgcn_global_load_lds((const __attribute__((address_space(1))) unsigned int*)g,
                                   (__attribute__((address_space(3))) unsigned int*)l, 16, 0, 0);
}

// ---------------- K1: group-norm partial stats ----------------
// grid 1024 = 128 (b,g) groups x 8 splits; contiguous 32768 floats per block
__global__ __launch_bounds__(256) void k_stats(const float* __restrict__ x, float* __restrict__ part) {
  int bid = blockIdx.x;
  int bg = bid >> 3, sp = bid & 7;
  const float4* p = (const float4*)(x + (size_t)bg * GELEMS + (size_t)sp * 32768);
  int t = threadIdx.x;
  float s = 0.f, ss = 0.f;
#pragma unroll
  for (int i = 0; i < 32; ++i) {
    float4 v = p[i * 256 + t];
    s += v.x + v.y + v.z + v.w;
    ss += v.x * v.x + v.y * v.y + v.z * v.z + v.w * v.w;
  }
#pragma unroll
  for (int off = 32; off; off >>= 1) { s += __shfl_down(s, off); ss += __shfl_down(ss, off); }
  __shared__ float red[8];
  int wid = t >> 6;
  if ((t & 63) == 0) { red[wid * 2] = s; red[wid * 2 + 1] = ss; }
  __syncthreads();
  if (t == 0) {
    float S = red[0] + red[2] + red[4] + red[6];
    float Q = red[1] + red[3] + red[5] + red[7];
    part[bid * 2] = S; part[bid * 2 + 1] = Q;
  }
}

// ---------------- K2: Mw = proj_w @ qkv_w[r(.),:]  (512^3 bf16 MFMA) ----------------
// grid 64 = 8x8 tiles of 64x64, 256 thr (4 waves 2x2), BK=32
__global__ __launch_bounds__(256) void k_mw(const float* __restrict__ pw, const float* __restrict__ qw,
                                            float* __restrict__ mw, unsigned short* __restrict__ mwbf) {
  __shared__ __align__(16) unsigned short Asb[64 * 32];  // [c2][k]
  __shared__ __align__(16) unsigned short Bsb[64 * 32];  // [c][k] (transposed in LDS)
  int t = threadIdx.x;
  int bm = (blockIdx.x >> 3) * 64;
  int bn = (blockIdx.x & 7) * 64;
  int w = t >> 6, l = t & 63;
  int wm = (w >> 1) * 32, wn = (w & 1) * 32;
  int fr = l & 15, fk = (l >> 4) * 8;
  f32x4 acc[2][2] = {};
  for (int k0 = 0; k0 < 512; k0 += 32) {
#pragma unroll
    for (int i = 0; i < 2; ++i) {            // A: 64 rows x 32 k of proj_w
      int e = i * 256 + t;
      int row = e >> 3, f4 = e & 7;
      float4 v = *(const float4*)&pw[(size_t)(bm + row) * 512 + k0 + f4 * 4];
      us4 pk; pk[0] = f2bf(v.x); pk[1] = f2bf(v.y); pk[2] = f2bf(v.z); pk[3] = f2bf(v.w);
      *(us4*)&Asb[row * 32 + f4 * 4] = pk;
    }
#pragma unroll
    for (int i = 0; i < 2; ++i) {            // B: 32 rows (cv) x 64 cols (c), transpose to [c][cv]
      int e = i * 256 + t;
      int row = e >> 4, f4 = e & 15;
      float4 v = *(const float4*)&qw[(size_t)qrow(k0 + row) * 512 + bn + f4 * 4];
      Bsb[(f4 * 4 + 0) * 32 + row] = f2bf(v.x);
      Bsb[(f4 * 4 + 1) * 32 + row] = f2bf(v.y);
      Bsb[(f4 * 4 + 2) * 32 + row] = f2bf(v.z);
      Bsb[(f4 * 4 + 3) * 32 + row] = f2bf(v.w);
    }
    __syncthreads();
    bf16x8 a[2], bfr[2];
#pragma unroll
    for (int i = 0; i < 2; ++i) a[i] = *(const bf16x8*)&Asb[(wm + i * 16 + fr) * 32 + fk];
#pragma unroll
    for (int j = 0; j < 2; ++j) bfr[j] = *(const bf16x8*)&Bsb[(wn + j * 16 + fr) * 32 + fk];
#pragma unroll
    for (int i = 0; i < 2; ++i)
#pragma unroll
      for (int j = 0; j < 2; ++j)
        acc[i][j] = __builtin_amdgcn_mfma_f32_16x16x32_bf16(a[i], bfr[j], acc[i][j], 0, 0, 0);
    __syncthreads();
  }
#pragma unroll
  for (int i = 0; i < 2; ++i)
#pragma unroll
    for (int j = 0; j < 2; ++j)
#pragma unroll
      for (int r = 0; r < 4; ++r) {
        int row = bm + wm + i * 16 + (l >> 4) * 4 + r;
        int col = bn + wn + j * 16 + (l & 15);
        float v = acc[i][j][r];
        mw[(size_t)row * 512 + col] = v;
        mwbf[(size_t)row * 512 + col] = f2bf(v);
      }
}

// ---------------- K3: finalize stats -> A[b,c], bias2[b,c2] ----------------
__global__ __launch_bounds__(256) void k_finalize(const float* __restrict__ part, const float* __restrict__ mw,
    const float* __restrict__ ng, const float* __restrict__ nb, const float* __restrict__ pw,
    const float* __restrict__ qb, const float* __restrict__ pb,
    float* __restrict__ afac, float* __restrict__ bias2) {
  int b = blockIdx.x, t = threadIdx.x;
  __shared__ float mean_s[8], rstd_s[8], Bc_s[512];
  if (t < 8) {
    float S = 0.f, Q = 0.f;
    for (int i = 0; i < 8; ++i) {
      S += part[((b * 8 + t) * 8 + i) * 2];
      Q += part[((b * 8 + t) * 8 + i) * 2 + 1];
    }
    float mean = S * (1.f / 262144.f);
    float var = Q * (1.f / 262144.f) - mean * mean;
    mean_s[t] = mean;
    rstd_s[t] = rsqrtf(var + 1e-5f);
  }
  __syncthreads();
#pragma unroll
  for (int i = 0; i < 2; ++i) {
    int c = t + i * 256;
    int g = c >> 6;
    float A = rstd_s[g] * ng[c];
    float Bc = nb[c] - mean_s[g] * A;
    afac[b * 512 + c] = A;
    Bc_s[c] = Bc;
  }
  __syncthreads();
#pragma unroll
  for (int i = 0; i < 2; ++i) {
    int c2 = t + i * 256;
    float acc = pb[c2];
    for (int h = 0; h < 4; ++h)
      for (int m = 0; m < 32; ++m) {
        float4 q4 = *(const float4*)&qb[h * 384 + 256 + m * 4];
        float4 p4 = *(const float4*)&pw[(size_t)c2 * 512 + h * 128 + m * 4];
        acc += p4.x * q4.x + p4.y * q4.y + p4.z * q4.z + p4.w * q4.w;
      }
    const float4* mr = (const float4*)&mw[(size_t)c2 * 512];
    float a2 = 0.f;
    for (int c = 0; c < 128; ++c) {
      float4 m4 = mr[c];
      float4 b4 = *(const float4*)&Bc_s[c * 4];
      a2 += m4.x * b4.x + m4.y * b4.y + m4.z * b4.z + m4.w * b4.w;
    }
    bias2[b * 512 + c2] = acc + a2;
  }
}

// ---------------- K2b: xbfT[b][s][c] = bf16(A[b,c] * x[b,c,s])  (64x64 LDS transpose) ----------------
#define TS 72   // padded c-stride (144 B, 16B-aligned)
__global__ __launch_bounds__(256) void k_cvt(const float* __restrict__ x, const float* __restrict__ afac,
                                             unsigned short* __restrict__ xbft) {
  __shared__ __align__(16) unsigned short T[64 * TS];
  __shared__ float Af[64];
  int bid = blockIdx.x;
  int b = bid >> 9, rem = bid & 511, ct = rem >> 6, st = rem & 63;
  int c0 = ct * 64, s0 = st * 64;
  int t = threadIdx.x;
  if (t < 64) Af[t] = afac[b * 512 + c0 + t];
  __syncthreads();
#pragma unroll
  for (int i = 0; i < 4; ++i) {
    int q = i * 256 + t;
    int row = q >> 4, f4 = q & 15;           // row = c_local, 16 float4 per row
    float4 v = *(const float4*)&x[((size_t)(b * 512 + c0 + row)) * SS + s0 + f4 * 4];
    float a = Af[row];
    int cblk = row >> 3, cidx = row & 7;
    float vv[4] = {v.x, v.y, v.z, v.w};
#pragma unroll
    for (int j = 0; j < 4; ++j) {
      int s = f4 * 4 + j;
      T[s * TS + ((cblk ^ (s & 7)) * 8 + cidx)] = f2bf(vv[j] * a);
    }
  }
  __syncthreads();
#pragma unroll
  for (int i = 0; i < 2; ++i) {
    int e = i * 256 + t;
    int sr = e >> 3, c8 = e & 7;
    uint4 v = *(const uint4*)&T[sr * TS + ((c8 ^ (sr & 7)) * 8)];
    *(uint4*)&xbft[((size_t)b * SS + s0 + sr) * 512 + c0 + c8 * 8] = v;
  }
}

// ---------------- K4: out = Mw@(A*x) + bias2 + x   (bf16 MFMA, m97 structure) ----------------
__global__ __launch_bounds__(256) void k_gemm(const unsigned short* __restrict__ mwbf,
    const unsigned short* __restrict__ xbft, const float* __restrict__ x,
    const float* __restrict__ bias2, float* __restrict__ out) {
  __shared__ __align__(16) unsigned short Ab[128 * 32];
  __shared__ __align__(16) unsigned short Bb[128 * 32];
  int bid0 = blockIdx.x;
  int bid = (bid0 & 7) * 256 + (bid0 >> 3);          // XCD swizzle (2048 % 8 == 0)
  int b = bid >> 7, rem = bid & 127, nt = rem >> 2, mt = rem & 3;
  int m0 = mt * 128, s0 = nt * 128;
  int t = threadIdx.x, w = t >> 6, l = t & 63;
  int wm = (w >> 1) * 64, wn = (w & 1) * 64;
  const unsigned short* Ag = mwbf + (size_t)m0 * CC;
  const unsigned short* Bg = xbft + ((size_t)b * SS + s0) * CC;
  int lr = l >> 2, lk = (l & 3) * 8;
  int fr = l & 15, fk = (l >> 4) * 8;
  f32x4 acc[4][4] = {};
  for (int k0 = 0; k0 < CC; k0 += 32) {
#pragma unroll
    for (int q = 0; q < 2; ++q) {
      int row = w * 32 + q * 16;
      gl_lds16(Ag + (size_t)(row + lr) * CC + k0 + lk, &Ab[row * 32]);
      gl_lds16(Bg + (size_t)(row + lr) * CC + k0 + lk, &Bb[row * 32]);
    }
    __syncthreads();
    bf16x8 af[4], bfr[4];
#pragma unroll
    for (int i = 0; i < 4; ++i) af[i] = *(const bf16x8*)&Ab[(wm + i * 16 + fr) * 32 + fk];
#pragma unroll
    for (int j = 0; j < 4; ++j) bfr[j] = *(const bf16x8*)&Bb[(wn + j * 16 + fr) * 32 + fk];
#pragma unroll
    for (int i = 0; i < 4; ++i)
#pragma unroll
      for (int j = 0; j < 4; ++j)
        acc[i][j] = __builtin_amdgcn_mfma_f32_16x16x32_bf16(af[i], bfr[j], acc[i][j], 0, 0, 0);
    __syncthreads();
  }
  int c2b = m0 + wm, sb = s0 + wn;
  float bi[4][4];
#pragma unroll
  for (int i = 0; i < 4; ++i)
#pragma unroll
    for (int r = 0; r < 4; ++r)
      bi[i][r] = bias2[b * CC + c2b + i * 16 + (l >> 4) * 4 + r];
#pragma unroll
  for (int i = 0; i < 4; ++i)
#pragma unroll
    for (int j = 0; j < 4; ++j)
#pragma unroll
      for (int r = 0; r < 4; ++r) {
        int c2 = c2b + i * 16 + (l >> 4) * 4 + r;
        int s = sb + j * 16 + (l & 15);
        size_t oi = ((size_t)(b * CC + c2)) * SS + s;
        out[oi] = acc[i][j][r] + bi[i][r] + x[oi];
      }
}

// ---------------- K4fb: fallback GEMM (no xbfT; reg-staged, in-kernel convert) ----------------
__global__ __launch_bounds__(256) void k_gemm_fb(const unsigned short* __restrict__ mwbf,
    const float* __restrict__ x, const float* __restrict__ afac,
    const float* __restrict__ bias2, float* __restrict__ out) {
  __shared__ __align__(16) unsigned short Ab[128 * 32];
  __shared__ __align__(16) unsigned short Bb[128 * 32];   // [s_local][k]
  __shared__ float Afs[512];
  int bid0 = blockIdx.x;
  int bid = (bid0 & 7) * 256 + (bid0 >> 3);
  int b = bid >> 7, rem = bid & 127, nt = rem >> 2, mt = rem & 3;
  int m0 = mt * 128, s0 = nt * 128;
  int t = threadIdx.x, w = t >> 6, l = t & 63;
  int wm = (w >> 1) * 64, wn = (w & 1) * 64;
  const unsigned short* Ag = mwbf + (size_t)m0 * CC;
  int lr = l >> 2, lk = (l & 3) * 8;
  int fr = l & 15, fk = (l >> 4) * 8;
  for (int i = t; i < 512; i += 256) Afs[i] = afac[b * CC + i];
  __syncthreads();
  f32x4 acc[4][4] = {};
  for (int k0 = 0; k0 < CC; k0 += 32) {
#pragma unroll
    for (int q = 0; q < 2; ++q) {
      int row = w * 32 + q * 16;
      gl_lds16(Ag + (size_t)(row + lr) * CC + k0 + lk, &Ab[row * 32]);
    }
#pragma unroll
    for (int i2 = 0; i2 < 4; ++i2) {          // B: x[b][k0+kr][s0 + 0..128) -> Bb[s][k]
      int e = i2 * 256 + t;
      int row = e >> 5, f4 = e & 31;
      float4 v = *(const float4*)&x[((size_t)(b * CC + k0 + row)) * SS + s0 + f4 * 4];
      float a = Afs[k0 + row];
      Bb[(f4 * 4 + 0) * 32 + row] = f2bf(v.x * a);
      Bb[(f4 * 4 + 1) * 32 + row] = f2bf(v.y * a);
      Bb[(f4 * 4 + 2) * 32 + row] = f2bf(v.z * a);
      Bb[(f4 * 4 + 3) * 32 + row] = f2bf(v.w * a);
    }
    __syncthreads();
    bf16x8 af[4], bfr[4];
#pragma unroll
    for (int i = 0; i < 4; ++i) af[i] = *(const bf16x8*)&Ab[(wm + i * 16 + fr) * 32 + fk];
#pragma unroll
    for (int j = 0; j < 4; ++j) bfr[j] = *(const bf16x8*)&Bb[(wn + j * 16 + fr) * 32 + fk];
#pragma unroll
    for (int i = 0; i < 4; ++i)
#pragma unroll
      for (int j = 0; j < 4; ++j)
        acc[i][j] = __builtin_amdgcn_mfma_f32_16x16x32_bf16(af[i], bfr[j], acc[i][j], 0, 0, 0);
    __syncthreads();
  }
  int c2b = m0 + wm, sb = s0 + wn;
  float bi[4][4];
#pragma unroll
  for (int i = 0; i < 4; ++i)
#pragma unroll
    for (int r = 0; r < 4; ++r)
      bi[i][r] = bias2[b * CC + c2b + i * 16 + (l >> 4) * 4 + r];
#pragma unroll
  for (int i = 0; i < 4; ++i)
#pragma unroll
    for (int j = 0; j < 4; ++j)
#pragma unroll
      for (int r = 0; r < 4; ++r) {
        int c2 = c2b + i * 16 + (l >> 4) * 4 + r;
        int s = sb + j * 16 + (l & 15);
        size_t oi = ((size_t)(b * CC + c2)) * SS + s;
        out[oi] = acc[i][j][r] + bi[i][r] + x[oi];
      }
}

extern "C" void kernel_launch(void* const* d_in, const int* in_sizes, int n_in,
                              void* d_out, int out_size, void* d_ws, size_t ws_size,
                              hipStream_t stream) {
  const float* x = (const float*)d_in[0];
  const float* ng = (const float*)d_in[1];
  const float* nb = (const float*)d_in[2];
  const float* qw = (const float*)d_in[3];
  const float* qb = (const float*)d_in[4];
  const float* pw = (const float*)d_in[5];
  const float* pb = (const float*)d_in[6];
  float* out = (float*)d_out;
  char* ws = (char*)d_ws;

  float* part = (float*)(ws + 0);                       //   8 KB
  float* afac = (float*)(ws + 8192);                    //  32 KB
  float* bias2 = (float*)(ws + 40960);                  //  32 KB
  float* mw = (float*)(ws + 73728);                     //   1 MB
  unsigned short* mwbf = (unsigned short*)(ws + 1122304); // 512 KB
  unsigned short* xbft = (unsigned short*)(ws + (size_t)(2u << 20)); // 64 MB

  bool fast = ws_size >= (size_t)(2u << 20) + (size_t)BB * SS * CC * 2;

  k_stats<<<1024, 256, 0, stream>>>(x, part);
  k_mw<<<64, 256, 0, stream>>>(pw, qw, mw, mwbf);
  k_finalize<<<16, 256, 0, stream>>>(part, mw, ng, nb, pw, qb, pb, afac, bias2);
  if (fast) {
    k_cvt<<<8192, 256, 0, stream>>>(x, afac, xbft);
    k_gemm<<<2048, 256, 0, stream>>>(mwbf, xbft, x, bias2, out);
  } else {
    k_gemm_fb<<<2048, 256, 0, stream>>>(mwbf, x, afac, bias2, out);
  }
}

// Round 2
// 232.814 us; speedup vs baseline: 1.1800x; 1.1800x over previous
//
#include <hip/hip_runtime.h>

#define CC 512
#define SS 4096
#define GELEMS 262144   // 64 ch * 4096 spatial per group

typedef __attribute__((ext_vector_type(8))) __bf16 bf16x8;
typedef __attribute__((ext_vector_type(4))) float f32x4;
typedef __attribute__((ext_vector_type(4))) unsigned short us4;
typedef __attribute__((ext_vector_type(8))) unsigned short us8;

__device__ __forceinline__ unsigned short f2bf(float f) {
  unsigned int u = __float_as_uint(f);
  u += 0x7fffu + ((u >> 16) & 1u);   // RNE
  return (unsigned short)(u >> 16);
}
__device__ __forceinline__ int qrow(int cv) { return ((cv >> 7) * 384) + 256 + (cv & 127); }

__device__ __forceinline__ void gl_lds16(const void* g, void* l) {
  __builtin_amdgcn_global_load_lds((const __attribute__((address_space(1))) unsigned int*)g,
                                   (__attribute__((address_space(3))) unsigned int*)l, 16, 0, 0);
}

// ---------------- K1 (fast): fused stats + bf16 transpose-convert ----------------
// grid 8192 = 16 b x 8 ct(group) x 64 st; 64c x 64s tile per block
// writes xbfT[b][s][c] = bf16(x[b][c][s])  (UNSCALED - scale folded into Mwb)
// and part[(b*8+g)*64 + st] = {sum, sumsq} over the 64x64 chunk
#define TS 72   // padded c-stride in LDS (144 B)
__global__ __launch_bounds__(256) void k_stats_cvt(const float* __restrict__ x,
    unsigned short* __restrict__ xbft, float* __restrict__ part) {
  __shared__ __align__(16) unsigned short T[64 * TS];
  __shared__ float red[8];
  int bid = blockIdx.x;
  int b = bid >> 9, rem = bid & 511, ct = rem >> 6, st = rem & 63;
  int c0 = ct * 64, s0 = st * 64;
  int t = threadIdx.x;
  float sm = 0.f, sq = 0.f;
#pragma unroll
  for (int i = 0; i < 4; ++i) {
    int q = i * 256 + t;
    int row = q >> 4, f4 = q & 15;           // row = c_local
    float4 v = *(const float4*)&x[((size_t)(b * 512 + c0 + row)) * SS + s0 + f4 * 4];
    sm += v.x + v.y + v.z + v.w;
    sq += v.x * v.x + v.y * v.y + v.z * v.z + v.w * v.w;
    int cblk = row >> 3, cidx = row & 7;
    float vv[4] = {v.x, v.y, v.z, v.w};
#pragma unroll
    for (int j = 0; j < 4; ++j) {
      int s = f4 * 4 + j;
      T[s * TS + ((cblk ^ (s & 7)) * 8 + cidx)] = f2bf(vv[j]);
    }
  }
#pragma unroll
  for (int off = 32; off; off >>= 1) { sm += __shfl_down(sm, off); sq += __shfl_down(sq, off); }
  __syncthreads();                            // T complete
  if ((t & 63) == 0) { red[t >> 6] = sm; red[4 + (t >> 6)] = sq; }
  __syncthreads();
  if (t == 0) {
    part[bid * 2] = red[0] + red[1] + red[2] + red[3];
    part[bid * 2 + 1] = red[4] + red[5] + red[6] + red[7];
  }
#pragma unroll
  for (int i = 0; i < 2; ++i) {
    int e = i * 256 + t;
    int sr = e >> 3, c8 = e & 7;
    uint4 v = *(const uint4*)&T[sr * TS + ((c8 ^ (sr & 7)) * 8)];
    *(uint4*)&xbft[((size_t)(b * SS) + s0 + sr) * 512 + c0 + c8 * 8] = v;
  }
}

// ---------------- K1 (fallback): stats only, part[(b*8+g)*8 + sp] ----------------
__global__ __launch_bounds__(256) void k_stats(const float* __restrict__ x, float* __restrict__ part) {
  int bid = blockIdx.x;
  int bg = bid >> 3, sp = bid & 7;
  const float4* p = (const float4*)(x + (size_t)bg * GELEMS + (size_t)sp * 32768);
  int t = threadIdx.x;
  float s = 0.f, ss = 0.f;
#pragma unroll
  for (int i = 0; i < 32; ++i) {
    float4 v = p[i * 256 + t];
    s += v.x + v.y + v.z + v.w;
    ss += v.x * v.x + v.y * v.y + v.z * v.z + v.w * v.w;
  }
#pragma unroll
  for (int off = 32; off; off >>= 1) { s += __shfl_down(s, off); ss += __shfl_down(ss, off); }
  __shared__ float red[8];
  int wid = t >> 6;
  if ((t & 63) == 0) { red[wid * 2] = s; red[wid * 2 + 1] = ss; }
  __syncthreads();
  if (t == 0) {
    part[bid * 2] = red[0] + red[2] + red[4] + red[6];
    part[bid * 2 + 1] = red[1] + red[3] + red[5] + red[7];
  }
}

// ---------------- K2: Mw = proj_w @ qkv_w[r(.),:]  (512^3 bf16 MFMA) ----------------
__global__ __launch_bounds__(256) void k_mw(const float* __restrict__ pw, const float* __restrict__ qw,
                                            float* __restrict__ mw, unsigned short* __restrict__ mwbf) {
  __shared__ __align__(16) unsigned short Asb[64 * 32];
  __shared__ __align__(16) unsigned short Bsb[64 * 32];
  int t = threadIdx.x;
  int bm = (blockIdx.x >> 3) * 64;
  int bn = (blockIdx.x & 7) * 64;
  int w = t >> 6, l = t & 63;
  int wm = (w >> 1) * 32, wn = (w & 1) * 32;
  int fr = l & 15, fk = (l >> 4) * 8;
  f32x4 acc[2][2] = {};
  for (int k0 = 0; k0 < 512; k0 += 32) {
#pragma unroll
    for (int i = 0; i < 2; ++i) {
      int e = i * 256 + t;
      int row = e >> 3, f4 = e & 7;
      float4 v = *(const float4*)&pw[(size_t)(bm + row) * 512 + k0 + f4 * 4];
      us4 pk; pk[0] = f2bf(v.x); pk[1] = f2bf(v.y); pk[2] = f2bf(v.z); pk[3] = f2bf(v.w);
      *(us4*)&Asb[row * 32 + f4 * 4] = pk;
    }
#pragma unroll
    for (int i = 0; i < 2; ++i) {
      int e = i * 256 + t;
      int row = e >> 4, f4 = e & 15;
      float4 v = *(const float4*)&qw[(size_t)qrow(k0 + row) * 512 + bn + f4 * 4];
      Bsb[(f4 * 4 + 0) * 32 + row] = f2bf(v.x);
      Bsb[(f4 * 4 + 1) * 32 + row] = f2bf(v.y);
      Bsb[(f4 * 4 + 2) * 32 + row] = f2bf(v.z);
      Bsb[(f4 * 4 + 3) * 32 + row] = f2bf(v.w);
    }
    __syncthreads();
    bf16x8 a[2], bfr[2];
#pragma unroll
    for (int i = 0; i < 2; ++i) a[i] = *(const bf16x8*)&Asb[(wm + i * 16 + fr) * 32 + fk];
#pragma unroll
    for (int j = 0; j < 2; ++j) bfr[j] = *(const bf16x8*)&Bsb[(wn + j * 16 + fr) * 32 + fk];
#pragma unroll
    for (int i = 0; i < 2; ++i)
#pragma unroll
      for (int j = 0; j < 2; ++j)
        acc[i][j] = __builtin_amdgcn_mfma_f32_16x16x32_bf16(a[i], bfr[j], acc[i][j], 0, 0, 0);
    __syncthreads();
  }
#pragma unroll
  for (int i = 0; i < 2; ++i)
#pragma unroll
    for (int j = 0; j < 2; ++j)
#pragma unroll
      for (int r = 0; r < 4; ++r) {
        int row = bm + wm + i * 16 + (l >> 4) * 4 + r;
        int col = bn + wn + j * 16 + (l & 15);
        float v = acc[i][j][r];
        mw[(size_t)row * 512 + col] = v;
        mwbf[(size_t)row * 512 + col] = f2bf(v);
      }
}

// ---------------- K3: finalize stats -> afac[b,c], Bc[b,c]  (grid 16, parallel) ----------------
__global__ __launch_bounds__(256) void k_fin(const float* __restrict__ part,
    const float* __restrict__ ng, const float* __restrict__ nb,
    float* __restrict__ afac, float* __restrict__ bcv, int np) {
  int b = blockIdx.x, t = threadIdx.x;
  __shared__ float mean_s[8], rstd_s[8];
  int g = t >> 5, i = t & 31;
  float S = 0.f, Q = 0.f;
  for (int k = i; k < np; k += 32) {
    S += part[((b * 8 + g) * np + k) * 2];
    Q += part[((b * 8 + g) * np + k) * 2 + 1];
  }
#pragma unroll
  for (int off = 16; off; off >>= 1) { S += __shfl_down(S, off, 32); Q += __shfl_down(Q, off, 32); }
  if (i == 0) {
    float mean = S * (1.f / 262144.f);
    float var = Q * (1.f / 262144.f) - mean * mean;
    mean_s[g] = mean;
    rstd_s[g] = rsqrtf(var + 1e-5f);
  }
  __syncthreads();
#pragma unroll
  for (int q = 0; q < 2; ++q) {
    int c = t + q * 256;
    int gg = c >> 6;
    float A = rstd_s[gg] * ng[c];
    afac[b * 512 + c] = A;
    bcv[b * 512 + c] = nb[c] - mean_s[gg] * A;
  }
}

// ---------------- K4: Mwb[b][c2][c] = bf16(Mw[c2][c] * afac[b][c])  (grid 2048) ----------------
__global__ __launch_bounds__(256) void k_mwb(const float* __restrict__ mw,
    const float* __restrict__ afac, unsigned short* __restrict__ mwb) {
  int bid = blockIdx.x;
  int b = bid >> 7, r4 = (bid & 127) * 4;
  int t = threadIdx.x;
  int c2 = r4 + (t >> 6), c = (t & 63) * 8;
  const float4* mr = (const float4*)&mw[(size_t)c2 * 512 + c];
  float4 m0 = mr[0], m1 = mr[1];
  const float4* ar = (const float4*)&afac[b * 512 + c];
  float4 a0 = ar[0], a1 = ar[1];
  us8 o;
  o[0] = f2bf(m0.x * a0.x); o[1] = f2bf(m0.y * a0.y); o[2] = f2bf(m0.z * a0.z); o[3] = f2bf(m0.w * a0.w);
  o[4] = f2bf(m1.x * a1.x); o[5] = f2bf(m1.y * a1.y); o[6] = f2bf(m1.z * a1.z); o[7] = f2bf(m1.w * a1.w);
  *(us8*)&mwb[((size_t)(b * 512 + c2)) * 512 + c] = o;
}

// ---------------- K5: bias2[b][c2] = pb + pw@qbr + Mw@Bc  (grid 128, wave-parallel) ----------------
__global__ __launch_bounds__(256) void k_bias2(const float* __restrict__ mw,
    const float* __restrict__ bcv, const float* __restrict__ pw,
    const float* __restrict__ qb, const float* __restrict__ pb, float* __restrict__ bias2) {
  int b = blockIdx.x >> 3, c2b = (blockIdx.x & 7) * 64;
  int t = threadIdx.x, w = t >> 6, l = t & 63;
  __shared__ float Bcs[512], Qbs[512];
  for (int i = t; i < 512; i += 256) { Bcs[i] = bcv[b * 512 + i]; Qbs[i] = qb[qrow(i)]; }
  __syncthreads();
  for (int it = 0; it < 16; ++it) {
    int c2 = c2b + w * 16 + it;
    const float4* pwr = (const float4*)&pw[(size_t)c2 * 512];
    const float4* mwr = (const float4*)&mw[(size_t)c2 * 512];
    float4 p0 = pwr[l * 2], p1 = pwr[l * 2 + 1];
    float4 m0 = mwr[l * 2], m1 = mwr[l * 2 + 1];
    const float4* qs = (const float4*)&Qbs[l * 8];
    const float4* bs = (const float4*)&Bcs[l * 8];
    float4 q0 = qs[0], q1 = qs[1], b0 = bs[0], b1 = bs[1];
    float acc = p0.x * q0.x + p0.y * q0.y + p0.z * q0.z + p0.w * q0.w
              + p1.x * q1.x + p1.y * q1.y + p1.z * q1.z + p1.w * q1.w
              + m0.x * b0.x + m0.y * b0.y + m0.z * b0.z + m0.w * b0.w
              + m1.x * b1.x + m1.y * b1.y + m1.z * b1.z + m1.w * b1.w;
#pragma unroll
    for (int off = 32; off; off >>= 1) acc += __shfl_down(acc, off);
    if (l == 0) bias2[b * 512 + c2] = acc + pb[c2];
  }
}

// ---------------- K6: out = Mwb[b]@xbfT[b] + bias2 + x  (2-phase dbuf MFMA GEMM) ----------------
__global__ __launch_bounds__(256) void k_gemm2(const unsigned short* __restrict__ mwb,
    const unsigned short* __restrict__ xbft, const float* __restrict__ x,
    const float* __restrict__ bias2, float* __restrict__ out) {
  __shared__ __align__(16) unsigned short Ab[2][128 * 32];
  __shared__ __align__(16) unsigned short Bb[2][128 * 32];
  int bid0 = blockIdx.x;
  int bid = (bid0 & 7) * 256 + (bid0 >> 3);          // XCD swizzle (2048 % 8 == 0)
  int b = bid >> 7, rem = bid & 127, nt = rem >> 2, mt = rem & 3;
  int m0 = mt * 128, s0 = nt * 128;
  int t = threadIdx.x, w = t >> 6, l = t & 63;
  int wm = (w >> 1) * 64, wn = (w & 1) * 64;
  const unsigned short* Ag = mwb + ((size_t)b * 512 + m0) * 512;
  const unsigned short* Bg = xbft + ((size_t)b * SS + s0) * 512;
  int lr = l >> 2, lk = (l & 3) * 8;
  int fr = l & 15, fk = (l >> 4) * 8;
  f32x4 acc[4][4] = {};

  auto stage = [&](int buf, int k0) {
    int row = w * 32;
    gl_lds16(Ag + (size_t)(row + lr) * 512 + k0 + lk, &Ab[buf][row * 32]);
    gl_lds16(Ag + (size_t)(row + 16 + lr) * 512 + k0 + lk, &Ab[buf][(row + 16) * 32]);
    gl_lds16(Bg + (size_t)(row + lr) * 512 + k0 + lk, &Bb[buf][row * 32]);
    gl_lds16(Bg + (size_t)(row + 16 + lr) * 512 + k0 + lk, &Bb[buf][(row + 16) * 32]);
  };
  auto compute = [&](int buf) {
    bf16x8 af[4], bfr[4];
#pragma unroll
    for (int i = 0; i < 4; ++i) af[i] = *(const bf16x8*)&Ab[buf][(wm + i * 16 + fr) * 32 + fk];
#pragma unroll
    for (int j = 0; j < 4; ++j) bfr[j] = *(const bf16x8*)&Bb[buf][(wn + j * 16 + fr) * 32 + fk];
#pragma unroll
    for (int i = 0; i < 4; ++i)
#pragma unroll
      for (int j = 0; j < 4; ++j)
        acc[i][j] = __builtin_amdgcn_mfma_f32_16x16x32_bf16(af[i], bfr[j], acc[i][j], 0, 0, 0);
  };

  stage(0, 0);
  __syncthreads();
  for (int it = 0; it < 15; ++it) {
    int cur = it & 1;
    stage(cur ^ 1, (it + 1) * 32);   // next-tile loads in flight during compute
    compute(cur);
    __syncthreads();                 // drains vmcnt(0): next buffer ready
  }
  compute(1);

  int c2b = m0 + wm, sb = s0 + wn;
  float bi[4][4];
#pragma unroll
  for (int i = 0; i < 4; ++i)
#pragma unroll
    for (int r = 0; r < 4; ++r)
      bi[i][r] = bias2[b * CC + c2b + i * 16 + (l >> 4) * 4 + r];
#pragma unroll
  for (int i = 0; i < 4; ++i)
#pragma unroll
    for (int j = 0; j < 4; ++j)
#pragma unroll
      for (int r = 0; r < 4; ++r) {
        int c2 = c2b + i * 16 + (l >> 4) * 4 + r;
        int s = sb + j * 16 + (l & 15);
        size_t oi = ((size_t)(b * CC + c2)) * SS + s;
        out[oi] = acc[i][j][r] + bi[i][r] + x[oi];
      }
}

// ---------------- K6fb: fallback GEMM (reg-staged, in-kernel convert + scale) ----------------
__global__ __launch_bounds__(256) void k_gemm_fb(const unsigned short* __restrict__ mwbf,
    const float* __restrict__ x, const float* __restrict__ afac,
    const float* __restrict__ bias2, float* __restrict__ out) {
  __shared__ __align__(16) unsigned short Ab[128 * 32];
  __shared__ __align__(16) unsigned short Bb[128 * 32];
  __shared__ float Afs[512];
  int bid0 = blockIdx.x;
  int bid = (bid0 & 7) * 256 + (bid0 >> 3);
  int b = bid >> 7, rem = bid & 127, nt = rem >> 2, mt = rem & 3;
  int m0 = mt * 128, s0 = nt * 128;
  int t = threadIdx.x, w = t >> 6, l = t & 63;
  int wm = (w >> 1) * 64, wn = (w & 1) * 64;
  const unsigned short* Ag = mwbf + (size_t)m0 * CC;
  int lr = l >> 2, lk = (l & 3) * 8;
  int fr = l & 15, fk = (l >> 4) * 8;
  for (int i = t; i < 512; i += 256) Afs[i] = afac[b * CC + i];
  __syncthreads();
  f32x4 acc[4][4] = {};
  for (int k0 = 0; k0 < CC; k0 += 32) {
#pragma unroll
    for (int q = 0; q < 2; ++q) {
      int row = w * 32 + q * 16;
      gl_lds16(Ag + (size_t)(row + lr) * CC + k0 + lk, &Ab[row * 32]);
    }
#pragma unroll
    for (int i2 = 0; i2 < 4; ++i2) {
      int e = i2 * 256 + t;
      int row = e >> 5, f4 = e & 31;
      float4 v = *(const float4*)&x[((size_t)(b * CC + k0 + row)) * SS + s0 + f4 * 4];
      float a = Afs[k0 + row];
      Bb[(f4 * 4 + 0) * 32 + row] = f2bf(v.x * a);
      Bb[(f4 * 4 + 1) * 32 + row] = f2bf(v.y * a);
      Bb[(f4 * 4 + 2) * 32 + row] = f2bf(v.z * a);
      Bb[(f4 * 4 + 3) * 32 + row] = f2bf(v.w * a);
    }
    __syncthreads();
    bf16x8 af[4], bfr[4];
#pragma unroll
    for (int i = 0; i < 4; ++i) af[i] = *(const bf16x8*)&Ab[(wm + i * 16 + fr) * 32 + fk];
#pragma unroll
    for (int j = 0; j < 4; ++j) bfr[j] = *(const bf16x8*)&Bb[(wn + j * 16 + fr) * 32 + fk];
#pragma unroll
    for (int i = 0; i < 4; ++i)
#pragma unroll
      for (int j = 0; j < 4; ++j)
        acc[i][j] = __builtin_amdgcn_mfma_f32_16x16x32_bf16(af[i], bfr[j], acc[i][j], 0, 0, 0);
    __syncthreads();
  }
  int c2b = m0 + wm, sb = s0 + wn;
  float bi[4][4];
#pragma unroll
  for (int i = 0; i < 4; ++i)
#pragma unroll
    for (int r = 0; r < 4; ++r)
      bi[i][r] = bias2[b * CC + c2b + i * 16 + (l >> 4) * 4 + r];
#pragma unroll
  for (int i = 0; i < 4; ++i)
#pragma unroll
    for (int j = 0; j < 4; ++j)
#pragma unroll
      for (int r = 0; r < 4; ++r) {
        int c2 = c2b + i * 16 + (l >> 4) * 4 + r;
        int s = sb + j * 16 + (l & 15);
        size_t oi = ((size_t)(b * CC + c2)) * SS + s;
        out[oi] = acc[i][j][r] + bi[i][r] + x[oi];
      }
}

extern "C" void kernel_launch(void* const* d_in, const int* in_sizes, int n_in,
                              void* d_out, int out_size, void* d_ws, size_t ws_size,
                              hipStream_t stream) {
  const float* x = (const float*)d_in[0];
  const float* ng = (const float*)d_in[1];
  const float* nb = (const float*)d_in[2];
  const float* qw = (const float*)d_in[3];
  const float* qb = (const float*)d_in[4];
  const float* pw = (const float*)d_in[5];
  const float* pb = (const float*)d_in[6];
  float* out = (float*)d_out;
  char* ws = (char*)d_ws;

  float* part = (float*)(ws + 0);                          //  64 KB (fast) / 8 KB (fb)
  float* afac = (float*)(ws + 65536);                      //  32 KB
  float* bcv = (float*)(ws + 98304);                       //  32 KB
  float* bias2 = (float*)(ws + 131072);                    //  32 KB
  float* mw = (float*)(ws + 163840);                       //   1 MB
  unsigned short* mwbf = (unsigned short*)(ws + 1212416);  // 512 KB
  unsigned short* mwb = (unsigned short*)(ws + 1736704);   //   8 MB
  unsigned short* xbft = (unsigned short*)(ws + 10125312); //  64 MB

  bool fast = ws_size >= 77234176ull;

  if (fast) {
    k_stats_cvt<<<8192, 256, 0, stream>>>(x, xbft, part);
    k_mw<<<64, 256, 0, stream>>>(pw, qw, mw, mwbf);
    k_fin<<<16, 256, 0, stream>>>(part, ng, nb, afac, bcv, 64);
    k_mwb<<<2048, 256, 0, stream>>>(mw, afac, mwb);
    k_bias2<<<128, 256, 0, stream>>>(mw, bcv, pw, qb, pb, bias2);
    k_gemm2<<<2048, 256, 0, stream>>>(mwb, xbft, x, bias2, out);
  } else {
    k_stats<<<1024, 256, 0, stream>>>(x, part);
    k_mw<<<64, 256, 0, stream>>>(pw, qw, mw, mwbf);
    k_fin<<<16, 256, 0, stream>>>(part, ng, nb, afac, bcv, 8);
    k_bias2<<<128, 256, 0, stream>>>(mw, bcv, pw, qb, pb, bias2);
    k_gemm_fb<<<2048, 256, 0, stream>>>(mwbf, x, afac, bias2, out);
  }
}

// Round 3
// 172.153 us; speedup vs baseline: 1.5957x; 1.3524x over previous
//
#include <hip/hip_runtime.h>

#define CC 512
#define SS 4096
#define GELEMS 262144   // 64 ch * 4096 spatial per group

typedef __attribute__((ext_vector_type(8))) __bf16 bf16x8;
typedef __attribute__((ext_vector_type(4))) float f32x4;
typedef __attribute__((ext_vector_type(4))) unsigned short us4;
typedef __attribute__((ext_vector_type(8))) unsigned short us8;

__device__ __forceinline__ unsigned short f2bf(float f) {
  unsigned int u = __float_as_uint(f);
  u += 0x7fffu + ((u >> 16) & 1u);   // RNE
  return (unsigned short)(u >> 16);
}
__device__ __forceinline__ int qrow(int cv) { return ((cv >> 7) * 384) + 256 + (cv & 127); }

__device__ __forceinline__ void gl_lds16(const void* g, void* l) {
  __builtin_amdgcn_global_load_lds((const __attribute__((address_space(1))) unsigned int*)g,
                                   (__attribute__((address_space(3))) unsigned int*)l, 16, 0, 0);
}

// ---------------- K1: group-norm partial stats (pure streaming read) ----------------
__global__ __launch_bounds__(256) void k_stats(const float* __restrict__ x, float* __restrict__ part) {
  int bid = blockIdx.x;
  int bg = bid >> 3, sp = bid & 7;
  const float4* p = (const float4*)(x + (size_t)bg * GELEMS + (size_t)sp * 32768);
  int t = threadIdx.x;
  float s = 0.f, ss = 0.f;
#pragma unroll
  for (int i = 0; i < 32; ++i) {
    float4 v = p[i * 256 + t];
    s += v.x + v.y + v.z + v.w;
    ss += v.x * v.x + v.y * v.y + v.z * v.z + v.w * v.w;
  }
#pragma unroll
  for (int off = 32; off; off >>= 1) { s += __shfl_down(s, off); ss += __shfl_down(ss, off); }
  __shared__ float red[8];
  int wid = t >> 6;
  if ((t & 63) == 0) { red[wid * 2] = s; red[wid * 2 + 1] = ss; }
  __syncthreads();
  if (t == 0) {
    part[bid * 2] = red[0] + red[2] + red[4] + red[6];
    part[bid * 2 + 1] = red[1] + red[3] + red[5] + red[7];
  }
}

// ---------------- K2: Mw = proj_w @ qkv_w[r(.),:]  (512^3 bf16 MFMA) ----------------
__global__ __launch_bounds__(256) void k_mw(const float* __restrict__ pw, const float* __restrict__ qw,
                                            float* __restrict__ mw, unsigned short* __restrict__ mwbf) {
  __shared__ __align__(16) unsigned short Asb[64 * 32];
  __shared__ __align__(16) unsigned short Bsb[64 * 32];
  int t = threadIdx.x;
  int bm = (blockIdx.x >> 3) * 64;
  int bn = (blockIdx.x & 7) * 64;
  int w = t >> 6, l = t & 63;
  int wm = (w >> 1) * 32, wn = (w & 1) * 32;
  int fr = l & 15, fk = (l >> 4) * 8;
  f32x4 acc[2][2] = {};
  for (int k0 = 0; k0 < 512; k0 += 32) {
#pragma unroll
    for (int i = 0; i < 2; ++i) {
      int e = i * 256 + t;
      int row = e >> 3, f4 = e & 7;
      float4 v = *(const float4*)&pw[(size_t)(bm + row) * 512 + k0 + f4 * 4];
      us4 pk; pk[0] = f2bf(v.x); pk[1] = f2bf(v.y); pk[2] = f2bf(v.z); pk[3] = f2bf(v.w);
      *(us4*)&Asb[row * 32 + f4 * 4] = pk;
    }
#pragma unroll
    for (int i = 0; i < 2; ++i) {
      int e = i * 256 + t;
      int row = e >> 4, f4 = e & 15;
      float4 v = *(const float4*)&qw[(size_t)qrow(k0 + row) * 512 + bn + f4 * 4];
      Bsb[(f4 * 4 + 0) * 32 + row] = f2bf(v.x);
      Bsb[(f4 * 4 + 1) * 32 + row] = f2bf(v.y);
      Bsb[(f4 * 4 + 2) * 32 + row] = f2bf(v.z);
      Bsb[(f4 * 4 + 3) * 32 + row] = f2bf(v.w);
    }
    __syncthreads();
    bf16x8 a[2], bfr[2];
#pragma unroll
    for (int i = 0; i < 2; ++i) a[i] = *(const bf16x8*)&Asb[(wm + i * 16 + fr) * 32 + fk];
#pragma unroll
    for (int j = 0; j < 2; ++j) bfr[j] = *(const bf16x8*)&Bsb[(wn + j * 16 + fr) * 32 + fk];
#pragma unroll
    for (int i = 0; i < 2; ++i)
#pragma unroll
      for (int j = 0; j < 2; ++j)
        acc[i][j] = __builtin_amdgcn_mfma_f32_16x16x32_bf16(a[i], bfr[j], acc[i][j], 0, 0, 0);
    __syncthreads();
  }
#pragma unroll
  for (int i = 0; i < 2; ++i)
#pragma unroll
    for (int j = 0; j < 2; ++j)
#pragma unroll
      for (int r = 0; r < 4; ++r) {
        int row = bm + wm + i * 16 + (l >> 4) * 4 + r;
        int col = bn + wn + j * 16 + (l & 15);
        float v = acc[i][j][r];
        mw[(size_t)row * 512 + col] = v;
        mwbf[(size_t)row * 512 + col] = f2bf(v);
      }
}

// ---------------- K3: finalize stats -> afac[b,c], Bc[b,c] ----------------
__global__ __launch_bounds__(256) void k_fin(const float* __restrict__ part,
    const float* __restrict__ ng, const float* __restrict__ nb,
    float* __restrict__ afac, float* __restrict__ bcv, int np) {
  int b = blockIdx.x, t = threadIdx.x;
  __shared__ float mean_s[8], rstd_s[8];
  int g = t >> 5, i = t & 31;
  float S = 0.f, Q = 0.f;
  for (int k = i; k < np; k += 32) {
    S += part[((b * 8 + g) * np + k) * 2];
    Q += part[((b * 8 + g) * np + k) * 2 + 1];
  }
#pragma unroll
  for (int off = 16; off; off >>= 1) { S += __shfl_down(S, off, 32); Q += __shfl_down(Q, off, 32); }
  if (i == 0) {
    float mean = S * (1.f / 262144.f);
    float var = Q * (1.f / 262144.f) - mean * mean;
    mean_s[g] = mean;
    rstd_s[g] = rsqrtf(var + 1e-5f);
  }
  __syncthreads();
#pragma unroll
  for (int q = 0; q < 2; ++q) {
    int c = t + q * 256;
    int gg = c >> 6;
    float A = rstd_s[gg] * ng[c];
    afac[b * 512 + c] = A;
    bcv[b * 512 + c] = nb[c] - mean_s[gg] * A;
  }
}

// ---------------- K4: Mwb[b][c2][c] = bf16(Mw[c2][c] * afac[b][c]) ----------------
__global__ __launch_bounds__(256) void k_mwb(const float* __restrict__ mw,
    const float* __restrict__ afac, unsigned short* __restrict__ mwb) {
  int bid = blockIdx.x;
  int b = bid >> 7, r4 = (bid & 127) * 4;
  int t = threadIdx.x;
  int c2 = r4 + (t >> 6), c = (t & 63) * 8;
  const float4* mr = (const float4*)&mw[(size_t)c2 * 512 + c];
  float4 m0 = mr[0], m1 = mr[1];
  const float4* ar = (const float4*)&afac[b * 512 + c];
  float4 a0 = ar[0], a1 = ar[1];
  us8 o;
  o[0] = f2bf(m0.x * a0.x); o[1] = f2bf(m0.y * a0.y); o[2] = f2bf(m0.z * a0.z); o[3] = f2bf(m0.w * a0.w);
  o[4] = f2bf(m1.x * a1.x); o[5] = f2bf(m1.y * a1.y); o[6] = f2bf(m1.z * a1.z); o[7] = f2bf(m1.w * a1.w);
  *(us8*)&mwb[((size_t)(b * 512 + c2)) * 512 + c] = o;
}

// ---------------- K5: bias2[b][c2] = pb + pw@qbr + Mw@Bc ----------------
__global__ __launch_bounds__(256) void k_bias2(const float* __restrict__ mw,
    const float* __restrict__ bcv, const float* __restrict__ pw,
    const float* __restrict__ qb, const float* __restrict__ pb, float* __restrict__ bias2) {
  int b = blockIdx.x >> 3, c2b = (blockIdx.x & 7) * 64;
  int t = threadIdx.x, w = t >> 6, l = t & 63;
  __shared__ float Bcs[512], Qbs[512];
  for (int i = t; i < 512; i += 256) { Bcs[i] = bcv[b * 512 + i]; Qbs[i] = qb[qrow(i)]; }
  __syncthreads();
  for (int it = 0; it < 16; ++it) {
    int c2 = c2b + w * 16 + it;
    const float4* pwr = (const float4*)&pw[(size_t)c2 * 512];
    const float4* mwr = (const float4*)&mw[(size_t)c2 * 512];
    float4 p0 = pwr[l * 2], p1 = pwr[l * 2 + 1];
    float4 m0 = mwr[l * 2], m1 = mwr[l * 2 + 1];
    const float4* qs = (const float4*)&Qbs[l * 8];
    const float4* bs = (const float4*)&Bcs[l * 8];
    float4 q0 = qs[0], q1 = qs[1], b0 = bs[0], b1 = bs[1];
    float acc = p0.x * q0.x + p0.y * q0.y + p0.z * q0.z + p0.w * q0.w
              + p1.x * q1.x + p1.y * q1.y + p1.z * q1.z + p1.w * q1.w
              + m0.x * b0.x + m0.y * b0.y + m0.z * b0.z + m0.w * b0.w
              + m1.x * b1.x + m1.y * b1.y + m1.z * b1.z + m1.w * b1.w;
#pragma unroll
    for (int off = 32; off; off >>= 1) acc += __shfl_down(acc, off);
    if (l == 0) bias2[b * 512 + c2] = acc + pb[c2];
  }
}

// ---------------- K6: fused out = Mwb[b]@bf16(x) + bias2 + x ----------------
// grid 1024 = 16 b x 64 s-tiles; 512 thr (8 waves), wave w owns rows [w*64, w*64+64)
// x-tile staged ONCE to LDS bf16 [s][c] (XOR-swizzled); A-frags direct from global (L2);
// residual re-read from LDS bf16. ONE barrier total, no K-loop barriers.
__global__ __launch_bounds__(512, 4) void k_fused(const unsigned short* __restrict__ mwb,
    const float* __restrict__ x, const float* __restrict__ bias2, float* __restrict__ out) {
  __shared__ __align__(16) unsigned short Bs[64 * 512];   // 64 KB, [s][c] bf16, byte ^= (s&7)<<4
  char* BsC = (char*)Bs;
  int bid0 = blockIdx.x;
  int bid = (bid0 & 7) * 128 + (bid0 >> 3);               // XCD swizzle (1024 % 8 == 0)
  int b = bid >> 6, st = bid & 63;
  int s0 = st * 64;
  int t = threadIdx.x, w = t >> 6, l = t & 63;
  int m0 = w * 64;
  int fr = l & 15, fq = l >> 4;

  // ---- stage: x[b][0:512][s0:s0+64] -> Bs (bf16, transposed, swizzled) ----
  const float* xb = x + (size_t)b * 512 * SS + s0;
#pragma unroll
  for (int it = 0; it < 8; ++it) {
    int kb = it * 64 + w * 8;
    us8 o;
#pragma unroll
    for (int j = 0; j < 8; ++j) o[j] = f2bf(xb[(size_t)(kb + j) * SS + l]);
    *(us8*)(BsC + ((l * 1024 + kb * 2) ^ ((l & 7) << 4))) = o;
  }

  // ---- A prefetch (global, L2-resident Mwb[b]) ----
  const unsigned short* Ag = mwb + (size_t)b * 512 * 512;
  bf16x8 fa[2][4];
#pragma unroll
  for (int i = 0; i < 4; ++i)
    fa[0][i] = *(const bf16x8*)&Ag[(size_t)(m0 + i * 16 + fr) * 512 + fq * 8];

  __syncthreads();   // the only barrier

  f32x4 acc[4][4] = {};
#pragma unroll
  for (int s8 = 0; s8 < 16; ++s8) {
    const int k0 = s8 * 32;
    const int cur = s8 & 1;
    if (s8 < 15) {
#pragma unroll
      for (int i = 0; i < 4; ++i)
        fa[cur ^ 1][i] = *(const bf16x8*)&Ag[(size_t)(m0 + i * 16 + fr) * 512 + k0 + 32 + fq * 8];
    }
    bf16x8 fb[4];
#pragma unroll
    for (int j = 0; j < 4; ++j) {
      int s = j * 16 + fr;
      fb[j] = *(const bf16x8*)(BsC + ((s * 1024 + (k0 + fq * 8) * 2) ^ ((s & 7) << 4)));
    }
#pragma unroll
    for (int i = 0; i < 4; ++i)
#pragma unroll
      for (int j = 0; j < 4; ++j)
        acc[i][j] = __builtin_amdgcn_mfma_f32_16x16x32_bf16(fa[cur][i], fb[j], acc[i][j], 0, 0, 0);
  }

  // ---- epilogue: + bias2 + residual(x from LDS bf16), write f32 ----
  float4 bi[4];
#pragma unroll
  for (int i = 0; i < 4; ++i)
    bi[i] = *(const float4*)&bias2[b * 512 + m0 + i * 16 + fq * 4];
  float* ob = out + (size_t)b * 512 * SS + s0;
#pragma unroll
  for (int i = 0; i < 4; ++i) {
    float bir[4] = {bi[i].x, bi[i].y, bi[i].z, bi[i].w};
#pragma unroll
    for (int j = 0; j < 4; ++j) {
      int s = j * 16 + fr;
#pragma unroll
      for (int r = 0; r < 4; ++r) {
        int c2 = m0 + i * 16 + fq * 4 + r;
        unsigned short rb = *(const unsigned short*)(BsC + ((s * 1024 + c2 * 2) ^ ((s & 7) << 4)));
        float res = __uint_as_float((unsigned int)rb << 16);
        ob[(size_t)c2 * SS + s] = acc[i][j][r] + bir[r] + res;
      }
    }
  }
}

// ---------------- K6fb: fallback GEMM (reg-staged, in-kernel convert + scale) ----------------
__global__ __launch_bounds__(256) void k_gemm_fb(const unsigned short* __restrict__ mwbf,
    const float* __restrict__ x, const float* __restrict__ afac,
    const float* __restrict__ bias2, float* __restrict__ out) {
  __shared__ __align__(16) unsigned short Ab[128 * 32];
  __shared__ __align__(16) unsigned short Bb[128 * 32];
  __shared__ float Afs[512];
  int bid0 = blockIdx.x;
  int bid = (bid0 & 7) * 256 + (bid0 >> 3);
  int b = bid >> 7, rem = bid & 127, nt = rem >> 2, mt = rem & 3;
  int m0 = mt * 128, s0 = nt * 128;
  int t = threadIdx.x, w = t >> 6, l = t & 63;
  int wm = (w >> 1) * 64, wn = (w & 1) * 64;
  const unsigned short* Ag = mwbf + (size_t)m0 * CC;
  int lr = l >> 2, lk = (l & 3) * 8;
  int fr = l & 15, fk = (l >> 4) * 8;
  for (int i = t; i < 512; i += 256) Afs[i] = afac[b * CC + i];
  __syncthreads();
  f32x4 acc[4][4] = {};
  for (int k0 = 0; k0 < CC; k0 += 32) {
#pragma unroll
    for (int q = 0; q < 2; ++q) {
      int row = w * 32 + q * 16;
      gl_lds16(Ag + (size_t)(row + lr) * CC + k0 + lk, &Ab[row * 32]);
    }
#pragma unroll
    for (int i2 = 0; i2 < 4; ++i2) {
      int e = i2 * 256 + t;
      int row = e >> 5, f4 = e & 31;
      float4 v = *(const float4*)&x[((size_t)(b * CC + k0 + row)) * SS + s0 + f4 * 4];
      float a = Afs[k0 + row];
      Bb[(f4 * 4 + 0) * 32 + row] = f2bf(v.x * a);
      Bb[(f4 * 4 + 1) * 32 + row] = f2bf(v.y * a);
      Bb[(f4 * 4 + 2) * 32 + row] = f2bf(v.z * a);
      Bb[(f4 * 4 + 3) * 32 + row] = f2bf(v.w * a);
    }
    __syncthreads();
    bf16x8 af[4], bfr[4];
#pragma unroll
    for (int i = 0; i < 4; ++i) af[i] = *(const bf16x8*)&Ab[(wm + i * 16 + fr) * 32 + fk];
#pragma unroll
    for (int j = 0; j < 4; ++j) bfr[j] = *(const bf16x8*)&Bb[(wn + j * 16 + fr) * 32 + fk];
#pragma unroll
    for (int i = 0; i < 4; ++i)
#pragma unroll
      for (int j = 0; j < 4; ++j)
        acc[i][j] = __builtin_amdgcn_mfma_f32_16x16x32_bf16(af[i], bfr[j], acc[i][j], 0, 0, 0);
    __syncthreads();
  }
  int c2b = m0 + wm, sb = s0 + wn;
  float bi[4][4];
#pragma unroll
  for (int i = 0; i < 4; ++i)
#pragma unroll
    for (int r = 0; r < 4; ++r)
      bi[i][r] = bias2[b * CC + c2b + i * 16 + (l >> 4) * 4 + r];
#pragma unroll
  for (int i = 0; i < 4; ++i)
#pragma unroll
    for (int j = 0; j < 4; ++j)
#pragma unroll
      for (int r = 0; r < 4; ++r) {
        int c2 = c2b + i * 16 + (l >> 4) * 4 + r;
        int s = sb + j * 16 + (l & 15);
        size_t oi = ((size_t)(b * CC + c2)) * SS + s;
        out[oi] = acc[i][j][r] + bi[i][r] + x[oi];
      }
}

extern "C" void kernel_launch(void* const* d_in, const int* in_sizes, int n_in,
                              void* d_out, int out_size, void* d_ws, size_t ws_size,
                              hipStream_t stream) {
  const float* x = (const float*)d_in[0];
  const float* ng = (const float*)d_in[1];
  const float* nb = (const float*)d_in[2];
  const float* qw = (const float*)d_in[3];
  const float* qb = (const float*)d_in[4];
  const float* pw = (const float*)d_in[5];
  const float* pb = (const float*)d_in[6];
  float* out = (float*)d_out;
  char* ws = (char*)d_ws;

  float* part = (float*)(ws + 0);                          //   8 KB
  float* afac = (float*)(ws + 65536);                      //  32 KB
  float* bcv = (float*)(ws + 98304);                       //  32 KB
  float* bias2 = (float*)(ws + 131072);                    //  32 KB
  float* mw = (float*)(ws + 163840);                       //   1 MB
  unsigned short* mwbf = (unsigned short*)(ws + 1212416);  // 512 KB
  unsigned short* mwb = (unsigned short*)(ws + 1736704);   //   8 MB -> end 10125312

  bool fast = ws_size >= 10125312ull;

  k_stats<<<1024, 256, 0, stream>>>(x, part);
  k_mw<<<64, 256, 0, stream>>>(pw, qw, mw, mwbf);
  k_fin<<<16, 256, 0, stream>>>(part, ng, nb, afac, bcv, 8);
  k_bias2<<<128, 256, 0, stream>>>(mw, bcv, pw, qb, pb, bias2);
  if (fast) {
    k_mwb<<<2048, 256, 0, stream>>>(mw, afac, mwb);
    k_fused<<<1024, 512, 0, stream>>>(mwb, x, bias2, out);
  } else {
    k_gemm_fb<<<2048, 256, 0, stream>>>(mwbf, x, afac, bias2, out);
  }
}